// Round 5
// baseline (219.614 us; speedup 1.0000x reference)
//
#include <hip/hip_runtime.h>

typedef unsigned short u16;
typedef unsigned int u32;
typedef __attribute__((ext_vector_type(8))) _Float16 half8;
typedef __attribute__((ext_vector_type(16))) float f32x16;

#define MFMA32(A, B, C) __builtin_amdgcn_mfma_f32_32x32x16_f16(A, B, C, 0, 0, 0)

constexpr int BN = 8;     // batches
constexpr int S = 4096;   // seq len
constexpr int D = 256;    // feature dim
constexpr int KB = 32;    // K/V tile rows
constexpr int NT = S / KB;            // 128 tiles
constexpr int TILE_U16 = KB * D;      // 8192 u16 = 16 KiB per image
constexpr int TP_U16 = 2 * TILE_U16;  // 16384 u16 = 32 KiB tile pack (enc|encT)

constexpr size_t WS_IMG_BYTES = (size_t)BN * NT * TP_U16 * 2;       // 32 MiB
constexpr size_t WS_ML_OFF = WS_IMG_BYTES;                          // float2[256*128]
constexpr size_t WS_ML_BYTES = 256 * 128 * 8;                       // 256 KiB
constexpr size_t WS_FLAG_OFF = WS_ML_OFF + WS_ML_BYTES;
constexpr size_t WS_NEED = WS_FLAG_OFF + 2 * 256 * 4;

__device__ __forceinline__ u32 pk2h(float a, float b) {
  union { _Float16 h[2]; u32 u; } x;
  x.h[0] = (_Float16)a; x.h[1] = (_Float16)b;
  return x.u;
}

__device__ __forceinline__ void gload_lds16(const void* g, void* l) {
  __builtin_amdgcn_global_load_lds((__attribute__((address_space(1))) void*)(void*)g,
                                   (__attribute__((address_space(3))) void*)l, 16, 0, 0);
}

// ---------------------------------------------------------------------------
// Convert enc (f32) into MFMA-fragment-ordered f16 tile packs:
// pack(b,t) = [ enc_img (8192 u16) | encT_img (8192 u16) ], 32 KiB contiguous.
// enc_img  group(c,h,i): off ((c*2+h)*32+i)*8  = enc[t*32+i][c*16+h*8+0..7]
// encT_img group(ds,ic,h,dd): off (((ds*2+ic)*2+h)*32+dd)*8 = enc[t*32+ic*16+h*8+j][ds*32+dd]
// ---------------------------------------------------------------------------
__global__ __launch_bounds__(256) void convert_enc(const float* __restrict__ enc,
                                                   u16* __restrict__ ws) {
  const int blk = blockIdx.x;
  const int b = blk & 7;
  const int tp = blk >> 3;  // tile pair 0..63
  const int tid = threadIdx.x;

  const float* encb = enc + (size_t)b * S * D;

  // ---- phase A: enc images, 2 tiles x 1024 groups ----
#pragma unroll
  for (int it = 0; it < 8; ++it) {
    int gg = it * 256 + tid;        // 0..2047
    int t = tp * 2 + (gg >> 10);
    int g = gg & 1023;              // (c*2+h)*32 + i
    int i = g & 31;
    int ch = g >> 5;
    int d0 = ch * 8;
    const float* src = encb + (size_t)(t * 32 + i) * D + d0;
    float4 x = *(const float4*)src;
    float4 y = *(const float4*)(src + 4);
    uint4 o;
    o.x = pk2h(x.x, x.y); o.y = pk2h(x.z, x.w);
    o.z = pk2h(y.x, y.y); o.w = pk2h(y.z, y.w);
    *(uint4*)(ws + (size_t)(b * NT + t) * TP_U16 + g * 8) = o;
  }

  // ---- phase B: encT images, 2 tiles x 128 blocklets (8i x 8d) ----
  {
    int t = tp * 2 + (tid >> 7);
    int r = tid & 127;
    int o = r >> 5;       // i-oct: ic=o>>1, h=o&1
    int e = r & 31;       // d-oct
    int i0 = o * 8;
    int d0 = e * 8;
    float v[8][8];
#pragma unroll
    for (int rr = 0; rr < 8; ++rr) {
      const float* src = encb + (size_t)(t * 32 + i0 + rr) * D + d0;
      *(float4*)&v[rr][0] = *(const float4*)src;
      *(float4*)&v[rr][4] = *(const float4*)(src + 4);
    }
    int dsub = e >> 4;    // wait: dsub = d0>>5 = e>>2
    dsub = e >> 2;
    u16* dst = ws + (size_t)(b * NT + t) * TP_U16 + TILE_U16 +
               ((dsub * 4 + o) * 32 + (e & 3) * 8) * 8;
#pragma unroll
    for (int k = 0; k < 8; ++k) {
      uint4 q;
      q.x = pk2h(v[0][k], v[1][k]); q.y = pk2h(v[2][k], v[3][k]);
      q.z = pk2h(v[4][k], v[5][k]); q.w = pk2h(v[6][k], v[7][k]);
      *(uint4*)(dst + k * 8) = q;
    }
  }
}

// ===========================================================================
// Main path: 512 blocks x 256 thr (4 waves x 32 q). Grid split-K: block kh
// handles tiles [kh*64, kh*64+64). 64 KiB LDS -> 2 blocks/CU (independent
// barriers -> cross-block phase overlap). Pair merge through `out` + ml strip.
// ===========================================================================
__global__ __launch_bounds__(256, 2) void attn_split(const u16* __restrict__ ws_img,
                                                     const float* __restrict__ dec,
                                                     float* __restrict__ out,
                                                     float2* __restrict__ mlws,
                                                     u32* __restrict__ flag0,
                                                     u32* __restrict__ flag1) {
  __shared__ u16 lds2[2][TP_U16];  // 2 x 32 KiB tile packs
  __shared__ int role_s;

  const int tid = threadIdx.x;
  const int w = tid >> 6;        // wave 0..3
  const int lane = tid & 63;
  const int h = lane >> 5;
  const int l31 = lane & 31;

  const int blk = blockIdx.x;
  const int b = blk & 7;                 // batch -> XCD affinity
  const int qc = (blk >> 3) & 31;        // q chunk
  const int kh = blk >> 8;               // K half
  const int pair = blk & 255;
  const int q0 = qc << 7;                // QBLK = 128
  const int qw = q0 + w * 32;

  const char* gtile = (const char*)(ws_img + (size_t)(b * NT + kh * 64) * TP_U16);
  const float* decb = dec + (size_t)b * S * D;

  // ---- Q fragments (B-operand): lane q=l31, k=c*16+h*8+j; pre-scaled log2e ----
  const float LOG2E = 1.4426950408889634f;
  half8 qf[16];
#pragma unroll
  for (int c = 0; c < 16; ++c) {
    const float* p = decb + (size_t)(qw + l31) * D + c * 16 + h * 8;
    float4 x = *(const float4*)p;
    float4 y = *(const float4*)(p + 4);
    union { u32 u[4]; half8 v; } uu;
    uu.u[0] = pk2h(x.x * LOG2E, x.y * LOG2E);
    uu.u[1] = pk2h(x.z * LOG2E, x.w * LOG2E);
    uu.u[2] = pk2h(y.x * LOG2E, y.y * LOG2E);
    uu.u[3] = pk2h(y.z * LOG2E, y.w * LOG2E);
    qf[c] = uu.v;
  }

  // ---- staging: 4 waves split one 32 KiB pack, linear ----
  auto stage = [&](int buf, size_t goff) {
    const char* gs = gtile + goff + w * 8192 + lane * 16;
    char* ls = (char*)&lds2[buf][0] + w * 8192;
#pragma unroll
    for (int it = 0; it < 8; ++it)
      gload_lds16(gs + it * 1024, ls + it * 1024);
  };

  f32x16 acc[8] = {};   // O^T raw
  float mrun = -1e30f;
  float lrun = 0.f;

  stage(0, 0);
  __syncthreads();

  for (int j = 0; j < 64; ++j) {
    const int cur = j & 1;
    if (j + 1 < 64) stage(cur ^ 1, (size_t)(j + 1) * 32768);

    // ---- S^T = enc . Q^T ----
    f32x16 s0 = {}, s1 = {};
    const char* eb = (const char*)&lds2[cur][0];
    __builtin_amdgcn_s_setprio(1);
#pragma unroll
    for (int c = 0; c < 16; c += 2) {
      half8 a0 = *(const half8*)(eb + ((c + 0) * 2 + h) * 512 + l31 * 16);
      half8 a1 = *(const half8*)(eb + ((c + 1) * 2 + h) * 512 + l31 * 16);
      s0 = MFMA32(a0, qf[c + 0], s0);
      s1 = MFMA32(a1, qf[c + 1], s1);
    }
    __builtin_amdgcn_s_setprio(0);
    f32x16 st = s0 + s1;

    // ---- online softmax (log2 domain), defer-max ----
    float x0 = fmaxf(st[0], st[1]), x1 = fmaxf(st[2], st[3]);
    float x2 = fmaxf(st[4], st[5]), x3 = fmaxf(st[6], st[7]);
    float x4 = fmaxf(st[8], st[9]), x5 = fmaxf(st[10], st[11]);
    float x6 = fmaxf(st[12], st[13]), x7 = fmaxf(st[14], st[15]);
    x0 = fmaxf(x0, x1); x2 = fmaxf(x2, x3); x4 = fmaxf(x4, x5); x6 = fmaxf(x6, x7);
    x0 = fmaxf(x0, x2); x4 = fmaxf(x4, x6);
    float tm = fmaxf(x0, x4);
    tm = fmaxf(tm, __shfl_xor(tm, 32));
    if (__any(tm > mrun + 11.5f)) {
      float mnew = fmaxf(mrun, tm);
      float alpha = __builtin_amdgcn_exp2f(mrun - mnew);
      mrun = mnew;
      lrun *= alpha;
#pragma unroll
      for (int ds = 0; ds < 8; ++ds)
#pragma unroll
        for (int r = 0; r < 16; ++r) acc[ds][r] *= alpha;
    }
    float p[16];
#pragma unroll
    for (int r = 0; r < 16; ++r) p[r] = __builtin_amdgcn_exp2f(st[r] - mrun);
    float y0 = (p[0] + p[1]) + (p[2] + p[3]);
    float y1 = (p[4] + p[5]) + (p[6] + p[7]);
    float y2 = (p[8] + p[9]) + (p[10] + p[11]);
    float y3 = (p[12] + p[13]) + (p[14] + p[15]);
    float rs = (y0 + y1) + (y2 + y3);
    rs += __shfl_xor(rs, 32);
    lrun += rs;

    // ---- pack P^T to f16 ----
    u32 pkw[8];
#pragma unroll
    for (int rq = 0; rq < 4; ++rq) {
      pkw[rq * 2 + 0] = pk2h(p[rq * 4 + 0], p[rq * 4 + 1]);
      pkw[rq * 2 + 1] = pk2h(p[rq * 4 + 2], p[rq * 4 + 3]);
    }
    half8 bfr[2];
#pragma unroll
    for (int ic = 0; ic < 2; ++ic) {
      u32 own0 = pkw[(2 * ic + h) * 2 + 0];
      u32 own1 = pkw[(2 * ic + h) * 2 + 1];
      u32 send0 = pkw[(2 * ic + 1 - h) * 2 + 0];
      u32 send1 = pkw[(2 * ic + 1 - h) * 2 + 1];
      u32 r0 = (u32)__shfl_xor((int)send0, 32);
      u32 r1 = (u32)__shfl_xor((int)send1, 32);
      union { u32 u[4]; half8 v; } bb;
      bb.u[0] = h ? r0 : own0;
      bb.u[1] = h ? r1 : own1;
      bb.u[2] = h ? own0 : r0;
      bb.u[3] = h ? own1 : r1;
      bfr[ic] = bb.v;
    }

    // ---- O^T += encT . P^T ----
    const char* tb = (const char*)&lds2[cur][0] + TILE_U16 * 2;
    __builtin_amdgcn_s_setprio(1);
#pragma unroll
    for (int ic = 0; ic < 2; ++ic) {
#pragma unroll
      for (int ds = 0; ds < 8; ++ds) {
        half8 vf = *(const half8*)(tb + ((ds * 2 + ic) * 2 + h) * 512 + l31 * 16);
        acc[ds] = MFMA32(vf, bfr[ic], acc[ds]);
      }
    }
    __builtin_amdgcn_s_setprio(0);

    __syncthreads();
  }

  // ---- pair merge protocol (last-arriver merges; symmetric => deterministic) ----
  float* orow = out + ((size_t)(b * S + qw + l31)) * D;

  if (tid == 0) {
    u32 r = __hip_atomic_fetch_add(&flag0[pair], 1u, __ATOMIC_ACQ_REL,
                                   __HIP_MEMORY_SCOPE_AGENT);
    role_s = (int)r;
  }
  __syncthreads();
  const int role = role_s;

  if (role == 0) {
    // first: publish raw acc into out slice + (m,l) into ml strip
    if (lane < 32) mlws[pair * 128 + w * 32 + l31] = make_float2(mrun, lrun);
#pragma unroll
    for (int ds = 0; ds < 8; ++ds) {
#pragma unroll
      for (int rq = 0; rq < 4; ++rq) {
        int d = ds * 32 + rq * 8 + h * 4;
        float4 o;
        o.x = acc[ds][rq * 4 + 0]; o.y = acc[ds][rq * 4 + 1];
        o.z = acc[ds][rq * 4 + 2]; o.w = acc[ds][rq * 4 + 3];
        *(float4*)(orow + d) = o;
      }
    }
    __syncthreads();  // all stores drained (vmcnt 0) before publish
    if (tid == 0) {
      __threadfence();
      __hip_atomic_store(&flag1[pair], 1u, __ATOMIC_RELEASE, __HIP_MEMORY_SCOPE_AGENT);
    }
  } else {
    if (tid == 0) {
      while (__hip_atomic_load(&flag1[pair], __ATOMIC_ACQUIRE,
                               __HIP_MEMORY_SCOPE_AGENT) == 0u)
        __builtin_amdgcn_s_sleep(2);
    }
    __syncthreads();
    float2 pml = mlws[pair * 128 + w * 32 + l31];
    float mn = fmaxf(mrun, pml.x);
    float a1 = __builtin_amdgcn_exp2f(mrun - mn);   // mine
    float a0 = __builtin_amdgcn_exp2f(pml.x - mn);  // partner
    float inv = 1.0f / (a0 * pml.y + a1 * lrun);
#pragma unroll
    for (int ds = 0; ds < 8; ++ds) {
#pragma unroll
      for (int rq = 0; rq < 4; ++rq) {
        int d = ds * 32 + rq * 8 + h * 4;
        float4 u = *(const float4*)(orow + d);
        float4 o;
        o.x = (a0 * u.x + a1 * acc[ds][rq * 4 + 0]) * inv;
        o.y = (a0 * u.y + a1 * acc[ds][rq * 4 + 1]) * inv;
        o.z = (a0 * u.z + a1 * acc[ds][rq * 4 + 2]) * inv;
        o.w = (a0 * u.w + a1 * acc[ds][rq * 4 + 3]) * inv;
        *(float4*)(orow + d) = o;
      }
    }
  }
}

// ===========================================================================
// Fallback (round-4 structure, packed-ws layout): 256 blocks x 512 thr,
// in-block split-K, LDS merge. Used only if ws is too small for the ml strip.
// ===========================================================================
__global__ __launch_bounds__(512, 2) void attn_fallback(const u16* __restrict__ ws_img,
                                                        const float* __restrict__ dec,
                                                        float* __restrict__ out) {
  __shared__ u16 lds[2][2][TP_U16];  // [stream][buf][pack] = 128 KiB

  const int tid = threadIdx.x;
  const int w = tid >> 6;
  const int wq = w & 3;
  const int kh = w >> 2;
  const int lane = tid & 63;
  const int h = lane >> 5;
  const int l31 = lane & 31;

  const int blk = blockIdx.x;
  const int b = blk & 7;
  const int q0 = (blk >> 3) << 7;
  const int qw = q0 + wq * 32;

  const u16* packs = ws_img + (size_t)b * NT * TP_U16;
  const float* decb = dec + (size_t)b * S * D;

  const float LOG2E = 1.4426950408889634f;
  half8 qf[16];
#pragma unroll
  for (int c = 0; c < 16; ++c) {
    const float* p = decb + (size_t)(qw + l31) * D + c * 16 + h * 8;
    float4 x = *(const float4*)p;
    float4 y = *(const float4*)(p + 4);
    union { u32 u[4]; half8 v; } uu;
    uu.u[0] = pk2h(x.x * LOG2E, x.y * LOG2E);
    uu.u[1] = pk2h(x.z * LOG2E, x.w * LOG2E);
    uu.u[2] = pk2h(y.x * LOG2E, y.y * LOG2E);
    uu.u[3] = pk2h(y.z * LOG2E, y.w * LOG2E);
    qf[c] = uu.v;
  }

  auto stage = [&](int buf, int t) {
    const char* gs = (const char*)(packs + (size_t)t * TP_U16) + wq * 8192 + lane * 16;
    char* ls = (char*)&lds[kh][buf][0] + wq * 8192;
#pragma unroll
    for (int it = 0; it < 8; ++it)
      gload_lds16(gs + it * 1024, ls + it * 1024);
  };

  f32x16 acc[8] = {};
  float mrun = -1e30f;
  float lrun = 0.f;

  stage(0, kh);
  __syncthreads();

  for (int j = 0; j < 64; ++j) {
    const int cur = j & 1;
    if (j + 1 < 64) stage(cur ^ 1, 2 * (j + 1) + kh);

    f32x16 s0 = {}, s1 = {};
    const char* eb = (const char*)&lds[kh][cur][0];
#pragma unroll
    for (int c = 0; c < 16; c += 2) {
      half8 a0 = *(const half8*)(eb + ((c + 0) * 2 + h) * 512 + l31 * 16);
      half8 a1 = *(const half8*)(eb + ((c + 1) * 2 + h) * 512 + l31 * 16);
      s0 = MFMA32(a0, qf[c + 0], s0);
      s1 = MFMA32(a1, qf[c + 1], s1);
    }
    f32x16 st = s0 + s1;

    float x0 = fmaxf(st[0], st[1]), x1 = fmaxf(st[2], st[3]);
    float x2 = fmaxf(st[4], st[5]), x3 = fmaxf(st[6], st[7]);
    float x4 = fmaxf(st[8], st[9]), x5 = fmaxf(st[10], st[11]);
    float x6 = fmaxf(st[12], st[13]), x7 = fmaxf(st[14], st[15]);
    x0 = fmaxf(x0, x1); x2 = fmaxf(x2, x3); x4 = fmaxf(x4, x5); x6 = fmaxf(x6, x7);
    x0 = fmaxf(x0, x2); x4 = fmaxf(x4, x6);
    float tm = fmaxf(x0, x4);
    tm = fmaxf(tm, __shfl_xor(tm, 32));
    if (__any(tm > mrun + 11.5f)) {
      float mnew = fmaxf(mrun, tm);
      float alpha = __builtin_amdgcn_exp2f(mrun - mnew);
      mrun = mnew;
      lrun *= alpha;
#pragma unroll
      for (int ds = 0; ds < 8; ++ds)
#pragma unroll
        for (int r = 0; r < 16; ++r) acc[ds][r] *= alpha;
    }
    float p[16];
#pragma unroll
    for (int r = 0; r < 16; ++r) p[r] = __builtin_amdgcn_exp2f(st[r] - mrun);
    float y0 = (p[0] + p[1]) + (p[2] + p[3]);
    float y1 = (p[4] + p[5]) + (p[6] + p[7]);
    float y2 = (p[8] + p[9]) + (p[10] + p[11]);
    float y3 = (p[12] + p[13]) + (p[14] + p[15]);
    float rs = (y0 + y1) + (y2 + y3);
    rs += __shfl_xor(rs, 32);
    lrun += rs;

    u32 pkw[8];
#pragma unroll
    for (int rq = 0; rq < 4; ++rq) {
      pkw[rq * 2 + 0] = pk2h(p[rq * 4 + 0], p[rq * 4 + 1]);
      pkw[rq * 2 + 1] = pk2h(p[rq * 4 + 2], p[rq * 4 + 3]);
    }
    half8 bfr[2];
#pragma unroll
    for (int ic = 0; ic < 2; ++ic) {
      u32 own0 = pkw[(2 * ic + h) * 2 + 0];
      u32 own1 = pkw[(2 * ic + h) * 2 + 1];
      u32 send0 = pkw[(2 * ic + 1 - h) * 2 + 0];
      u32 send1 = pkw[(2 * ic + 1 - h) * 2 + 1];
      u32 r0 = (u32)__shfl_xor((int)send0, 32);
      u32 r1 = (u32)__shfl_xor((int)send1, 32);
      union { u32 u[4]; half8 v; } bb;
      bb.u[0] = h ? r0 : own0;
      bb.u[1] = h ? r1 : own1;
      bb.u[2] = h ? own0 : r0;
      bb.u[3] = h ? own1 : r1;
      bfr[ic] = bb.v;
    }

    const char* tb = (const char*)&lds[kh][cur][0] + TILE_U16 * 2;
#pragma unroll
    for (int ic = 0; ic < 2; ++ic) {
#pragma unroll
      for (int ds = 0; ds < 8; ++ds) {
        half8 vf = *(const half8*)(tb + ((ds * 2 + ic) * 2 + h) * 512 + l31 * 16);
        acc[ds] = MFMA32(vf, bfr[ic], acc[ds]);
      }
    }

    __syncthreads();
  }

  float* fb = (float*)&lds[0][0][0];
  constexpr int XS = 20;
  float* mlb = fb + 30208;

  if (kh == 1) {
    if (lane < 32) {
      mlb[wq * 64 + lane] = mrun;
      mlb[wq * 64 + 32 + lane] = lrun;
    }
#pragma unroll
    for (int d4 = 0; d4 < 4; ++d4) {
      float* dst = fb + ((wq * 4 + d4) * 64 + lane) * XS;
#pragma unroll
      for (int r4 = 0; r4 < 4; ++r4) {
        float4 v;
        v.x = acc[d4][r4 * 4 + 0]; v.y = acc[d4][r4 * 4 + 1];
        v.z = acc[d4][r4 * 4 + 2]; v.w = acc[d4][r4 * 4 + 3];
        *(float4*)(dst + r4 * 4) = v;
      }
    }
  }
  __syncthreads();

  float a0 = 0.f, a1 = 0.f, inv = 0.f;
  const int q = qw + l31;
  float* orow = out + ((size_t)(b * S + q)) * D;
  if (kh == 0) {
    float m1 = mlb[wq * 64 + l31];
    float l1 = mlb[wq * 64 + 32 + l31];
    float mn = fmaxf(mrun, m1);
    a0 = __builtin_amdgcn_exp2f(mrun - mn);
    a1 = __builtin_amdgcn_exp2f(m1 - mn);
    inv = 1.0f / (a0 * lrun + a1 * l1);
#pragma unroll
    for (int d4 = 0; d4 < 4; ++d4) {
      const float* src = fb + ((wq * 4 + d4) * 64 + lane) * XS;
#pragma unroll
      for (int rq = 0; rq < 4; ++rq) {
        float4 u = *(const float4*)(src + rq * 4);
        int d = d4 * 32 + rq * 8 + h * 4;
        float4 o;
        o.x = (a0 * acc[d4][rq * 4 + 0] + a1 * u.x) * inv;
        o.y = (a0 * acc[d4][rq * 4 + 1] + a1 * u.y) * inv;
        o.z = (a0 * acc[d4][rq * 4 + 2] + a1 * u.z) * inv;
        o.w = (a0 * acc[d4][rq * 4 + 3] + a1 * u.w) * inv;
        *(float4*)(orow + d) = o;
      }
    }
  }
  __syncthreads();

  if (kh == 1) {
#pragma unroll
    for (int d4 = 0; d4 < 4; ++d4) {
      float* dst = fb + ((wq * 4 + d4) * 64 + lane) * XS;
#pragma unroll
      for (int r4 = 0; r4 < 4; ++r4) {
        float4 v;
        v.x = acc[d4 + 4][r4 * 4 + 0]; v.y = acc[d4 + 4][r4 * 4 + 1];
        v.z = acc[d4 + 4][r4 * 4 + 2]; v.w = acc[d4 + 4][r4 * 4 + 3];
        *(float4*)(dst + r4 * 4) = v;
      }
    }
  }
  __syncthreads();

  if (kh == 0) {
#pragma unroll
    for (int d4 = 0; d4 < 4; ++d4) {
      const float* src = fb + ((wq * 4 + d4) * 64 + lane) * XS;
#pragma unroll
      for (int rq = 0; rq < 4; ++rq) {
        float4 u = *(const float4*)(src + rq * 4);
        int d = (d4 + 4) * 32 + rq * 8 + h * 4;
        float4 o;
        o.x = (a0 * acc[d4 + 4][rq * 4 + 0] + a1 * u.x) * inv;
        o.y = (a0 * acc[d4 + 4][rq * 4 + 1] + a1 * u.y) * inv;
        o.z = (a0 * acc[d4 + 4][rq * 4 + 2] + a1 * u.z) * inv;
        o.w = (a0 * acc[d4 + 4][rq * 4 + 3] + a1 * u.w) * inv;
        *(float4*)(orow + d) = o;
      }
    }
  }
}

// ---------------------------------------------------------------------------
extern "C" void kernel_launch(void* const* d_in, const int* in_sizes, int n_in,
                              void* d_out, int out_size, void* d_ws, size_t ws_size,
                              hipStream_t stream) {
  const float* enc = (const float*)d_in[0];
  const float* dec = (const float*)d_in[1];
  float* out = (float*)d_out;

  u16* ws_img = (u16*)d_ws;

  convert_enc<<<BN * (S / 64), 256, 0, stream>>>(enc, ws_img);

  if (ws_size >= WS_NEED) {
    float2* mlws = (float2*)((char*)d_ws + WS_ML_OFF);
    u32* flags = (u32*)((char*)d_ws + WS_FLAG_OFF);
    hipMemsetAsync(flags, 0, 2 * 256 * 4, stream);
    attn_split<<<512, 256, 0, stream>>>(ws_img, dec, out, mlws, flags, flags + 256);
  } else {
    attn_fallback<<<BN * (S / 128), 512, 0, stream>>>(ws_img, dec, out);
  }
}

// Round 7
// 215.213 us; speedup vs baseline: 1.0204x; 1.0204x over previous
//
#include <hip/hip_runtime.h>

typedef unsigned short u16;
typedef unsigned int u32;
typedef __attribute__((ext_vector_type(8))) _Float16 half8;
typedef __attribute__((ext_vector_type(2))) __fp16 fp16x2;
typedef __attribute__((ext_vector_type(16))) float f32x16;

#define MFMA32(A, B, C) __builtin_amdgcn_mfma_f32_32x32x16_f16(A, B, C, 0, 0, 0)

constexpr int BN = 8;     // batches
constexpr int S = 4096;   // seq len
constexpr int D = 256;    // feature dim
constexpr int KB = 32;    // K/V tile rows
constexpr int NT = S / KB;            // 128 tiles
constexpr int TILE_U16 = KB * D;      // 8192 u16 = 16 KiB per image
constexpr int TP_U16 = 2 * TILE_U16;  // 32 KiB tile pack (enc|encT)

__device__ __forceinline__ u32 pk2h(float a, float b) {  // RNE (conversion path)
  union { _Float16 h[2]; u32 u; } x;
  x.h[0] = (_Float16)a; x.h[1] = (_Float16)b;
  return x.u;
}

__device__ __forceinline__ u32 pkrtz(float a, float b) {  // 1-inst pack (hot loop)
  union { fp16x2 h; u32 u; } x;
  x.h = __builtin_amdgcn_cvt_pkrtz(a, b);
  return x.u;
}

__device__ __forceinline__ void gload_lds16(const void* g, void* l) {
  __builtin_amdgcn_global_load_lds((__attribute__((address_space(1))) void*)(void*)g,
                                   (__attribute__((address_space(3))) void*)l, 16, 0, 0);
}

// ---------------------------------------------------------------------------
// Convert enc (f32) into MFMA-fragment-ordered f16 tile packs (validated):
// pack(b,t) = [ enc_img | encT_img ], 32 KiB contiguous; all attn ds_reads
// lane-linear b128, staging a plain linear global_load_lds copy.
// ---------------------------------------------------------------------------
__global__ __launch_bounds__(256) void convert_enc(const float* __restrict__ enc,
                                                   u16* __restrict__ ws) {
  const int blk = blockIdx.x;
  const int b = blk & 7;
  const int tp = blk >> 3;  // tile pair 0..63
  const int tid = threadIdx.x;

  const float* encb = enc + (size_t)b * S * D;

  // ---- phase A: enc images, 2 tiles x 1024 groups ----
#pragma unroll
  for (int it = 0; it < 8; ++it) {
    int gg = it * 256 + tid;        // 0..2047
    int t = tp * 2 + (gg >> 10);
    int g = gg & 1023;              // (c*2+h)*32 + i
    int i = g & 31;
    int ch = g >> 5;
    int d0 = ch * 8;
    const float* src = encb + (size_t)(t * 32 + i) * D + d0;
    float4 x = *(const float4*)src;
    float4 y = *(const float4*)(src + 4);
    uint4 o;
    o.x = pk2h(x.x, x.y); o.y = pk2h(x.z, x.w);
    o.z = pk2h(y.x, y.y); o.w = pk2h(y.z, y.w);
    *(uint4*)(ws + (size_t)(b * NT + t) * TP_U16 + g * 8) = o;
  }

  // ---- phase B: encT images, 2 tiles x 128 blocklets (8i x 8d) ----
  {
    int t = tp * 2 + (tid >> 7);
    int r = tid & 127;
    int o = r >> 5;       // i-oct: ic=o>>1, h=o&1
    int e = r & 31;       // d-oct
    int i0 = o * 8;
    int d0 = e * 8;
    float v[8][8];
#pragma unroll
    for (int rr = 0; rr < 8; ++rr) {
      const float* src = encb + (size_t)(t * 32 + i0 + rr) * D + d0;
      *(float4*)&v[rr][0] = *(const float4*)src;
      *(float4*)&v[rr][4] = *(const float4*)(src + 4);
    }
    int dsub = e >> 2;
    u16* dst = ws + (size_t)(b * NT + t) * TP_U16 + TILE_U16 +
               ((dsub * 4 + o) * 32 + (e & 3) * 8) * 8;
#pragma unroll
    for (int k = 0; k < 8; ++k) {
      uint4 q;
      q.x = pk2h(v[0][k], v[1][k]); q.y = pk2h(v[2][k], v[3][k]);
      q.z = pk2h(v[4][k], v[5][k]); q.w = pk2h(v[6][k], v[7][k]);
      *(uint4*)(dst + k * 8) = q;
    }
  }
}

// ---------------------------------------------------------------------------
// Flash attention, 8 waves, in-block split-K with ANTI-PHASE streams.
// 256 blocks x 512 thr. QBLK=128 (4 q-waves x 32 q) x 2 K-streams (kh=w>>2),
// stream kh handles tiles t=2j+kh. Each pass has two barrier regions:
//   stream 0 (staggered):  [SM+PV(t-1)] bar [stage(t+1); QK(t)] bar
//   stream 1 (natural):    [stage(t+1); QK(t)] bar [SM+PV(t)]   bar
// => every SIMD (one wave of each stream) sees MFMA work + one softmax in
// BOTH regions; VALU hides under MFMA by construction. LDS merge at end.
// ---------------------------------------------------------------------------
__global__ __launch_bounds__(512, 2) void attn_kernel(const u16* __restrict__ ws_img,
                                                      const float* __restrict__ dec,
                                                      float* __restrict__ out) {
  __shared__ u16 lds[2][2][TP_U16];  // [stream][buf][pack] = 128 KiB

  const int tid = threadIdx.x;
  const int w = tid >> 6;
  const int wq = w & 3;
  const int kh = w >> 2;
  const int lane = tid & 63;
  const int h = lane >> 5;
  const int l31 = lane & 31;

  const int blk = blockIdx.x;
  const int b = blk & 7;
  const int q0 = (blk >> 3) << 7;
  const int qw = q0 + wq * 32;

  const u16* packs = ws_img + (size_t)b * NT * TP_U16;
  const float* decb = dec + (size_t)b * S * D;

  // ---- Q fragments (B-operand): lane q=l31, k=c*16+h*8+j; pre-scaled log2e ----
  const float LOG2E = 1.4426950408889634f;
  half8 qf[16];
#pragma unroll
  for (int c = 0; c < 16; ++c) {
    const float* p = decb + (size_t)(qw + l31) * D + c * 16 + h * 8;
    float4 x = *(const float4*)p;
    float4 y = *(const float4*)(p + 4);
    union { u32 u[4]; half8 v; } uu;
    uu.u[0] = pk2h(x.x * LOG2E, x.y * LOG2E);
    uu.u[1] = pk2h(x.z * LOG2E, x.w * LOG2E);
    uu.u[2] = pk2h(y.x * LOG2E, y.y * LOG2E);
    uu.u[3] = pk2h(y.z * LOG2E, y.w * LOG2E);
    qf[c] = uu.v;
  }

  f32x16 acc[8] = {};   // O^T: [dsub]; lane: q=l31, d=dsub*32+(r&3)+8*(r>>2)+4h
  float mrun = -1e30f;  // running max (log2 domain)
  float lrun = 0.f;

  // 4 waves of a stream stage their stream's 32 KiB pack, 8 KiB each, linear
  auto stagef = [&](int buf, int t) {
    const char* gs = (const char*)(packs + (size_t)t * TP_U16) + wq * 8192 + lane * 16;
    char* ls = (char*)&lds[kh][buf][0] + wq * 8192;
#pragma unroll
    for (int it = 0; it < 8; ++it)
      gload_lds16(gs + it * 1024, ls + it * 1024);
  };

  auto qkf = [&](int buf) -> f32x16 {
    f32x16 s0 = {}, s1 = {};
    const char* eb = (const char*)&lds[kh][buf][0];
    __builtin_amdgcn_s_setprio(1);
#pragma unroll
    for (int c = 0; c < 16; c += 2) {
      half8 a0 = *(const half8*)(eb + ((c + 0) * 2 + h) * 512 + l31 * 16);
      half8 a1 = *(const half8*)(eb + ((c + 1) * 2 + h) * 512 + l31 * 16);
      s0 = MFMA32(a0, qf[c + 0], s0);
      s1 = MFMA32(a1, qf[c + 1], s1);
    }
    __builtin_amdgcn_s_setprio(0);
    return s0 + s1;
  };

  auto smpv = [&](const f32x16& st, int buf) {
    // online softmax (log2 domain), defer-max THR
    float x0 = fmaxf(fmaxf(st[0], st[1]), fmaxf(st[2], st[3]));
    float x1 = fmaxf(fmaxf(st[4], st[5]), fmaxf(st[6], st[7]));
    float x2 = fmaxf(fmaxf(st[8], st[9]), fmaxf(st[10], st[11]));
    float x3 = fmaxf(fmaxf(st[12], st[13]), fmaxf(st[14], st[15]));
    float tm = fmaxf(fmaxf(x0, x1), fmaxf(x2, x3));
    tm = fmaxf(tm, __shfl_xor(tm, 32));
    if (__any(tm > mrun + 11.5f)) {
      float mnew = fmaxf(mrun, tm);
      float alpha = __builtin_amdgcn_exp2f(mrun - mnew);
      mrun = mnew;
      lrun *= alpha;
#pragma unroll
      for (int ds = 0; ds < 8; ++ds)
#pragma unroll
        for (int r = 0; r < 16; ++r) acc[ds][r] *= alpha;
    }
    float p[16];
#pragma unroll
    for (int r = 0; r < 16; ++r) p[r] = __builtin_amdgcn_exp2f(st[r] - mrun);
    float y0 = (p[0] + p[1]) + (p[2] + p[3]);
    float y1 = (p[4] + p[5]) + (p[6] + p[7]);
    float y2 = (p[8] + p[9]) + (p[10] + p[11]);
    float y3 = (p[12] + p[13]) + (p[14] + p[15]);
    float rs = (y0 + y1) + (y2 + y3);
    rs += __shfl_xor(rs, 32);
    lrun += rs;

    // pack P^T to f16; pkw[rq*2+w2] covers i = 8*rq + 4h + 2*w2 + {0,1}
    u32 pkw[8];
#pragma unroll
    for (int rq = 0; rq < 4; ++rq) {
      pkw[rq * 2 + 0] = pkrtz(p[rq * 4 + 0], p[rq * 4 + 1]);
      pkw[rq * 2 + 1] = pkrtz(p[rq * 4 + 2], p[rq * 4 + 3]);
    }
    half8 bfr[2];
#pragma unroll
    for (int ic = 0; ic < 2; ++ic) {
      u32 own0 = pkw[(2 * ic + h) * 2 + 0];
      u32 own1 = pkw[(2 * ic + h) * 2 + 1];
      u32 send0 = pkw[(2 * ic + 1 - h) * 2 + 0];
      u32 send1 = pkw[(2 * ic + 1 - h) * 2 + 1];
      u32 r0 = (u32)__shfl_xor((int)send0, 32);
      u32 r1 = (u32)__shfl_xor((int)send1, 32);
      union { u32 u[4]; half8 v; } bb;
      bb.u[0] = h ? r0 : own0;
      bb.u[1] = h ? r1 : own1;
      bb.u[2] = h ? own0 : r0;
      bb.u[3] = h ? own1 : r1;
      bfr[ic] = bb.v;
    }

    const char* tb = (const char*)&lds[kh][buf][0] + TILE_U16 * 2;
    __builtin_amdgcn_s_setprio(1);
#pragma unroll
    for (int ic = 0; ic < 2; ++ic) {
#pragma unroll
      for (int ds = 0; ds < 8; ++ds) {
        half8 vf = *(const half8*)(tb + ((ds * 2 + ic) * 2 + h) * 512 + l31 * 16);
        acc[ds] = MFMA32(vf, bfr[ic], acc[ds]);
      }
    }
    __builtin_amdgcn_s_setprio(0);
  };

  f32x16 stp;

  // prologue: both streams stage tile_0(own) into buf0
  stagef(0, kh);
  __syncthreads();

  // pass j=0
  if (kh == 0) {
    __syncthreads();                       // bar_a (phase1 empty)
    stagef(1, 2); stp = qkf(0);
    __syncthreads();                       // bar_b
  } else {
    stagef(1, 3); stp = qkf(0);
    __syncthreads();                       // bar_a
    smpv(stp, 0);
    __syncthreads();                       // bar_b
  }

#pragma unroll 1
  for (int j = 1; j < 64; ++j) {
    if (kh == 0) {
      smpv(stp, (j - 1) & 1);              // SM+PV of tile t-1
      __syncthreads();                     // bar_a
      if (j <= 62) stagef((j + 1) & 1, 2 * (j + 1));
      stp = qkf(j & 1);                    // QK of tile t
      __syncthreads();                     // bar_b
    } else {
      if (j <= 62) stagef((j + 1) & 1, 2 * (j + 1) + 1);
      stp = qkf(j & 1);                    // QK of tile t
      __syncthreads();                     // bar_a
      smpv(stp, j & 1);                    // SM+PV of tile t
      __syncthreads();                     // bar_b
    }
  }

  // pass j=64 (drain stream 0's last tile; stream 1 idles through barriers)
  if (kh == 0) {
    smpv(stp, 1);
    __syncthreads();
    __syncthreads();
  } else {
    __syncthreads();
    __syncthreads();
  }

  // ---- merge the two K-streams through LDS ----
  float* fb = (float*)&lds[0][0][0];
  constexpr int XS = 20;
  float* mlb = fb + 30208;

  if (kh == 1) {
    if (lane < 32) {
      mlb[wq * 64 + lane] = mrun;
      mlb[wq * 64 + 32 + lane] = lrun;
    }
#pragma unroll
    for (int d4 = 0; d4 < 4; ++d4) {
      float* dst = fb + ((wq * 4 + d4) * 64 + lane) * XS;
#pragma unroll
      for (int r4 = 0; r4 < 4; ++r4) {
        float4 v;
        v.x = acc[d4][r4 * 4 + 0]; v.y = acc[d4][r4 * 4 + 1];
        v.z = acc[d4][r4 * 4 + 2]; v.w = acc[d4][r4 * 4 + 3];
        *(float4*)(dst + r4 * 4) = v;
      }
    }
  }
  __syncthreads();

  float a0 = 0.f, a1 = 0.f, inv = 0.f;
  const int q = qw + l31;
  float* orow = out + ((size_t)(b * S + q)) * D;
  if (kh == 0) {
    float m1 = mlb[wq * 64 + l31];
    float l1 = mlb[wq * 64 + 32 + l31];
    float mn = fmaxf(mrun, m1);
    a0 = __builtin_amdgcn_exp2f(mrun - mn);
    a1 = __builtin_amdgcn_exp2f(m1 - mn);
    inv = 1.0f / (a0 * lrun + a1 * l1);
#pragma unroll
    for (int d4 = 0; d4 < 4; ++d4) {
      const float* src = fb + ((wq * 4 + d4) * 64 + lane) * XS;
#pragma unroll
      for (int rq = 0; rq < 4; ++rq) {
        float4 u = *(const float4*)(src + rq * 4);
        int d = d4 * 32 + rq * 8 + h * 4;
        float4 o;
        o.x = (a0 * acc[d4][rq * 4 + 0] + a1 * u.x) * inv;
        o.y = (a0 * acc[d4][rq * 4 + 1] + a1 * u.y) * inv;
        o.z = (a0 * acc[d4][rq * 4 + 2] + a1 * u.z) * inv;
        o.w = (a0 * acc[d4][rq * 4 + 3] + a1 * u.w) * inv;
        *(float4*)(orow + d) = o;
      }
    }
  }
  __syncthreads();

  if (kh == 1) {
#pragma unroll
    for (int d4 = 0; d4 < 4; ++d4) {
      float* dst = fb + ((wq * 4 + d4) * 64 + lane) * XS;
#pragma unroll
      for (int r4 = 0; r4 < 4; ++r4) {
        float4 v;
        v.x = acc[d4 + 4][r4 * 4 + 0]; v.y = acc[d4 + 4][r4 * 4 + 1];
        v.z = acc[d4 + 4][r4 * 4 + 2]; v.w = acc[d4 + 4][r4 * 4 + 3];
        *(float4*)(dst + r4 * 4) = v;
      }
    }
  }
  __syncthreads();

  if (kh == 0) {
#pragma unroll
    for (int d4 = 0; d4 < 4; ++d4) {
      const float* src = fb + ((wq * 4 + d4) * 64 + lane) * XS;
#pragma unroll
      for (int rq = 0; rq < 4; ++rq) {
        float4 u = *(const float4*)(src + rq * 4);
        int d = (d4 + 4) * 32 + rq * 8 + h * 4;
        float4 o;
        o.x = (a0 * acc[d4 + 4][rq * 4 + 0] + a1 * u.x) * inv;
        o.y = (a0 * acc[d4 + 4][rq * 4 + 1] + a1 * u.y) * inv;
        o.z = (a0 * acc[d4 + 4][rq * 4 + 2] + a1 * u.z) * inv;
        o.w = (a0 * acc[d4 + 4][rq * 4 + 3] + a1 * u.w) * inv;
        *(float4*)(orow + d) = o;
      }
    }
  }
}

// ---------------------------------------------------------------------------
extern "C" void kernel_launch(void* const* d_in, const int* in_sizes, int n_in,
                              void* d_out, int out_size, void* d_ws, size_t ws_size,
                              hipStream_t stream) {
  const float* enc = (const float*)d_in[0];
  const float* dec = (const float*)d_in[1];
  float* out = (float*)d_out;

  u16* ws_img = (u16*)d_ws;

  convert_enc<<<BN * (S / 64), 256, 0, stream>>>(enc, ws_img);
  attn_kernel<<<BN * (S / 128), 512, 0, stream>>>(ws_img, dec, out);
}

// Round 8
// 192.543 us; speedup vs baseline: 1.1406x; 1.1177x over previous
//
#include <hip/hip_runtime.h>

typedef unsigned short u16;
typedef unsigned int u32;
typedef __attribute__((ext_vector_type(8))) _Float16 half8;
typedef __attribute__((ext_vector_type(2))) __fp16 fp16x2;
typedef __attribute__((ext_vector_type(16))) float f32x16;

#define MFMA32(A, B, C) __builtin_amdgcn_mfma_f32_32x32x16_f16(A, B, C, 0, 0, 0)

constexpr int BN = 8;     // batches
constexpr int S = 4096;   // seq len
constexpr int D = 256;    // feature dim
constexpr int KB = 32;    // K/V tile rows
constexpr int NT = S / KB;            // 128 tiles
constexpr int TILE_U16 = KB * D;      // 8192 u16 = 16 KiB per image
constexpr int TP_U16 = 2 * TILE_U16;  // 32 KiB tile pack (enc|encT)

__device__ __forceinline__ u32 pk2h(float a, float b) {  // RNE (conversion path)
  union { _Float16 h[2]; u32 u; } x;
  x.h[0] = (_Float16)a; x.h[1] = (_Float16)b;
  return x.u;
}

__device__ __forceinline__ u32 pkrtz(float a, float b) {  // 1-inst pack (hot loop)
  union { fp16x2 h; u32 u; } x;
  x.h = __builtin_amdgcn_cvt_pkrtz(a, b);
  return x.u;
}

__device__ __forceinline__ void gload_lds16(const void* g, void* l) {
  __builtin_amdgcn_global_load_lds((__attribute__((address_space(1))) void*)(void*)g,
                                   (__attribute__((address_space(3))) void*)l, 16, 0, 0);
}

// ---------------------------------------------------------------------------
// Convert enc (f32) into MFMA-fragment-ordered f16 tile packs (validated):
// pack(b,t) = [ enc_img | encT_img ], 32 KiB contiguous; all attn ds_reads
// lane-linear b128, staging a plain linear global_load_lds copy.
// ---------------------------------------------------------------------------
__global__ __launch_bounds__(256) void convert_enc(const float* __restrict__ enc,
                                                   u16* __restrict__ ws) {
  const int blk = blockIdx.x;
  const int b = blk & 7;
  const int tp = blk >> 3;  // tile pair 0..63
  const int tid = threadIdx.x;

  const float* encb = enc + (size_t)b * S * D;

  // ---- phase A: enc images, 2 tiles x 1024 groups ----
#pragma unroll
  for (int it = 0; it < 8; ++it) {
    int gg = it * 256 + tid;        // 0..2047
    int t = tp * 2 + (gg >> 10);
    int g = gg & 1023;              // (c*2+h)*32 + i
    int i = g & 31;
    int ch = g >> 5;
    int d0 = ch * 8;
    const float* src = encb + (size_t)(t * 32 + i) * D + d0;
    float4 x = *(const float4*)src;
    float4 y = *(const float4*)(src + 4);
    uint4 o;
    o.x = pk2h(x.x, x.y); o.y = pk2h(x.z, x.w);
    o.z = pk2h(y.x, y.y); o.w = pk2h(y.z, y.w);
    *(uint4*)(ws + (size_t)(b * NT + t) * TP_U16 + g * 8) = o;
  }

  // ---- phase B: encT images, 2 tiles x 128 blocklets (8i x 8d) ----
  {
    int t = tp * 2 + (tid >> 7);
    int r = tid & 127;
    int o = r >> 5;       // i-oct: ic=o>>1, h=o&1
    int e = r & 31;       // d-oct
    int i0 = o * 8;
    int d0 = e * 8;
    float v[8][8];
#pragma unroll
    for (int rr = 0; rr < 8; ++rr) {
      const float* src = encb + (size_t)(t * 32 + i0 + rr) * D + d0;
      *(float4*)&v[rr][0] = *(const float4*)src;
      *(float4*)&v[rr][4] = *(const float4*)(src + 4);
    }
    int dsub = e >> 2;
    u16* dst = ws + (size_t)(b * NT + t) * TP_U16 + TILE_U16 +
               ((dsub * 4 + o) * 32 + (e & 3) * 8) * 8;
#pragma unroll
    for (int k = 0; k < 8; ++k) {
      uint4 q;
      q.x = pk2h(v[0][k], v[1][k]); q.y = pk2h(v[2][k], v[3][k]);
      q.z = pk2h(v[4][k], v[5][k]); q.w = pk2h(v[6][k], v[7][k]);
      *(uint4*)(dst + k * 8) = q;
    }
  }
}

// ---------------------------------------------------------------------------
// Flash attention, 8 waves, in-block split-K, 3-DEEP PIPELINED pass:
//   pass j (per stream, tile t=2j+kh):
//     stage(t+1) | QK(t) | PV(t-1) | SM(t)   ... ONE barrier
// enc ring = 2 slots, encT ring = 3 slots per stream (80 KiB/stream, 160 total).
// PV(t-1) is independent of QK(t)/SM(t) => compiler overlaps MFMA and VALU
// within the wave; SM's only hard order is acc-rescale after PV (reg deps).
// ---------------------------------------------------------------------------
__global__ __launch_bounds__(512, 2) void attn_kernel(const u16* __restrict__ ws_img,
                                                      const float* __restrict__ dec,
                                                      float* __restrict__ out) {
  // [stream][slot]: slot 0-1 = enc ring, slot 2-4 = encT ring. 160 KiB total.
  __shared__ u16 LDSA[2][5][TILE_U16];

  const int tid = threadIdx.x;
  const int w = tid >> 6;
  const int wq = w & 3;
  const int kh = w >> 2;
  const int lane = tid & 63;
  const int h = lane >> 5;
  const int l31 = lane & 31;

  const int blk = blockIdx.x;
  const int b = blk & 7;               // batch -> XCD affinity
  const int q0 = (blk >> 3) << 7;      // QBLK = 128
  const int qw = q0 + wq * 32;

  const u16* packs = ws_img + (size_t)b * NT * TP_U16;
  const float* decb = dec + (size_t)b * S * D;

  // ---- Q fragments (B-operand): lane q=l31, k=c*16+h*8+j; pre-scaled log2e ----
  const float LOG2E = 1.4426950408889634f;
  half8 qf[16];
#pragma unroll
  for (int c = 0; c < 16; ++c) {
    const float* p = decb + (size_t)(qw + l31) * D + c * 16 + h * 8;
    float4 x = *(const float4*)p;
    float4 y = *(const float4*)(p + 4);
    union { u32 u[4]; half8 v; } uu;
    uu.u[0] = pk2h(x.x * LOG2E, x.y * LOG2E);
    uu.u[1] = pk2h(x.z * LOG2E, x.w * LOG2E);
    uu.u[2] = pk2h(y.x * LOG2E, y.y * LOG2E);
    uu.u[3] = pk2h(y.z * LOG2E, y.w * LOG2E);
    qf[c] = uu.v;
  }

  f32x16 acc[8] = {};   // O^T: [dsub]; lane: q=l31, d=dsub*32+(r&3)+8*(r>>2)+4h
  float mrun = -1e30f;  // running max (log2 domain)
  float lrun = 0.f;

  // stage tile t of this stream: enc half -> enc slot eslot, encT -> 2+tslot.
  // 4 waves of the stream move 32 KiB (8 KiB each): wq<2 -> enc, wq>=2 -> encT.
  auto stagef = [&](int t, int eslot, int tslot) {
    const char* gs = (const char*)(packs + (size_t)t * TP_U16) +
                     (wq >> 1) * 16384 + (wq & 1) * 8192 + lane * 16;
    char* ls = (char*)&LDSA[kh][(wq < 2) ? eslot : (2 + tslot)][0] + (wq & 1) * 8192;
#pragma unroll
    for (int it = 0; it < 8; ++it)
      gload_lds16(gs + it * 1024, ls + it * 1024);
  };

  half8 bfrA[2];  // P fragments of tile t-1 (consumed by PV this pass)
  half8 bfrB[2];  // P fragments of tile t   (produced by SM this pass)

  int e_cur = 0;                      // enc slot of tile j
  int t_prev = 2, t_cur = 0, t_next = 1;  // encT slots (j-1, j, j+1) mod 3

  // prologue: stage tile_0 of own stream
  stagef(kh, 0, 0);
  __syncthreads();

#pragma unroll 1
  for (int j = 0; j < 64; ++j) {
    // ---- stage(t+1) ----
    if (j < 63) stagef(2 * (j + 1) + kh, e_cur ^ 1, t_next);

    // ---- QK(t): S^T = enc . Q^T, dual chain ----
    f32x16 s0 = {}, s1 = {};
    {
      const char* eb = (const char*)&LDSA[kh][e_cur][0];
#pragma unroll
      for (int c = 0; c < 16; c += 2) {
        half8 a0 = *(const half8*)(eb + ((c + 0) * 2 + h) * 512 + l31 * 16);
        half8 a1 = *(const half8*)(eb + ((c + 1) * 2 + h) * 512 + l31 * 16);
        s0 = MFMA32(a0, qf[c + 0], s0);
        s1 = MFMA32(a1, qf[c + 1], s1);
      }
    }

    // ---- PV(t-1): independent of QK(t); overlaps SM below via scheduling ----
    if (j > 0) {
      const char* tb = (const char*)&LDSA[kh][2 + t_prev][0];
#pragma unroll
      for (int ic = 0; ic < 2; ++ic) {
#pragma unroll
        for (int ds = 0; ds < 8; ++ds) {
          half8 vf = *(const half8*)(tb + ((ds * 2 + ic) * 2 + h) * 512 + l31 * 16);
          acc[ds] = MFMA32(vf, bfrA[ic], acc[ds]);
        }
      }
    }

    // ---- SM(t): online softmax (log2 domain), defer-max, pack -> bfrB ----
    {
      f32x16 st = s0 + s1;
      float x0 = fmaxf(fmaxf(st[0], st[1]), fmaxf(st[2], st[3]));
      float x1 = fmaxf(fmaxf(st[4], st[5]), fmaxf(st[6], st[7]));
      float x2 = fmaxf(fmaxf(st[8], st[9]), fmaxf(st[10], st[11]));
      float x3 = fmaxf(fmaxf(st[12], st[13]), fmaxf(st[14], st[15]));
      float tm = fmaxf(fmaxf(x0, x1), fmaxf(x2, x3));
      tm = fmaxf(tm, __shfl_xor(tm, 32));
      if (__any(tm > mrun + 11.5f)) {
        float mnew = fmaxf(mrun, tm);
        float alpha = __builtin_amdgcn_exp2f(mrun - mnew);
        mrun = mnew;
        lrun *= alpha;
#pragma unroll
        for (int ds = 0; ds < 8; ++ds)
#pragma unroll
          for (int r = 0; r < 16; ++r) acc[ds][r] *= alpha;  // after PV (reg dep)
      }
#pragma unroll
      for (int r = 0; r < 16; ++r) st[r] = __builtin_amdgcn_exp2f(st[r] - mrun);
      float y0 = (st[0] + st[1]) + (st[2] + st[3]);
      float y1 = (st[4] + st[5]) + (st[6] + st[7]);
      float y2 = (st[8] + st[9]) + (st[10] + st[11]);
      float y3 = (st[12] + st[13]) + (st[14] + st[15]);
      float rs = (y0 + y1) + (y2 + y3);
      rs += __shfl_xor(rs, 32);
      lrun += rs;

      u32 pkw[8];
#pragma unroll
      for (int rq = 0; rq < 4; ++rq) {
        pkw[rq * 2 + 0] = pkrtz(st[rq * 4 + 0], st[rq * 4 + 1]);
        pkw[rq * 2 + 1] = pkrtz(st[rq * 4 + 2], st[rq * 4 + 3]);
      }
#pragma unroll
      for (int ic = 0; ic < 2; ++ic) {
        u32 own0 = pkw[(2 * ic + h) * 2 + 0];
        u32 own1 = pkw[(2 * ic + h) * 2 + 1];
        u32 send0 = pkw[(2 * ic + 1 - h) * 2 + 0];
        u32 send1 = pkw[(2 * ic + 1 - h) * 2 + 1];
        u32 r0 = (u32)__shfl_xor((int)send0, 32);
        u32 r1 = (u32)__shfl_xor((int)send1, 32);
        union { u32 u[4]; half8 v; } bb;
        bb.u[0] = h ? r0 : own0;
        bb.u[1] = h ? r1 : own1;
        bb.u[2] = h ? own0 : r0;
        bb.u[3] = h ? own1 : r1;
        bfrB[ic] = bb.v;
      }
    }

    __syncthreads();  // drains stage vmcnt; protects ring slots

    bfrA[0] = bfrB[0]; bfrA[1] = bfrB[1];
    e_cur ^= 1;
    t_prev = t_cur; t_cur = t_next; t_next = (t_next == 2) ? 0 : t_next + 1;
  }

  // ---- drain: PV of last tile ----
  {
    const char* tb = (const char*)&LDSA[kh][2 + t_prev][0];
#pragma unroll
    for (int ic = 0; ic < 2; ++ic) {
#pragma unroll
      for (int ds = 0; ds < 8; ++ds) {
        half8 vf = *(const half8*)(tb + ((ds * 2 + ic) * 2 + h) * 512 + l31 * 16);
        acc[ds] = MFMA32(vf, bfrA[ic], acc[ds]);
      }
    }
  }
  __syncthreads();

  // ---- merge the two K-streams through LDS (r4-validated) ----
  float* fb = (float*)&LDSA[0][0][0];
  constexpr int XS = 20;
  float* mlb = fb + 30208;

  if (kh == 1) {
    if (lane < 32) {
      mlb[wq * 64 + lane] = mrun;
      mlb[wq * 64 + 32 + lane] = lrun;
    }
#pragma unroll
    for (int d4 = 0; d4 < 4; ++d4) {
      float* dst = fb + ((wq * 4 + d4) * 64 + lane) * XS;
#pragma unroll
      for (int r4 = 0; r4 < 4; ++r4) {
        float4 v;
        v.x = acc[d4][r4 * 4 + 0]; v.y = acc[d4][r4 * 4 + 1];
        v.z = acc[d4][r4 * 4 + 2]; v.w = acc[d4][r4 * 4 + 3];
        *(float4*)(dst + r4 * 4) = v;
      }
    }
  }
  __syncthreads();

  float a0 = 0.f, a1 = 0.f, inv = 0.f;
  const int q = qw + l31;
  float* orow = out + ((size_t)(b * S + q)) * D;
  if (kh == 0) {
    float m1 = mlb[wq * 64 + l31];
    float l1 = mlb[wq * 64 + 32 + l31];
    float mn = fmaxf(mrun, m1);
    a0 = __builtin_amdgcn_exp2f(mrun - mn);
    a1 = __builtin_amdgcn_exp2f(m1 - mn);
    inv = 1.0f / (a0 * lrun + a1 * l1);
#pragma unroll
    for (int d4 = 0; d4 < 4; ++d4) {
      const float* src = fb + ((wq * 4 + d4) * 64 + lane) * XS;
#pragma unroll
      for (int rq = 0; rq < 4; ++rq) {
        float4 u = *(const float4*)(src + rq * 4);
        int d = d4 * 32 + rq * 8 + h * 4;
        float4 o;
        o.x = (a0 * acc[d4][rq * 4 + 0] + a1 * u.x) * inv;
        o.y = (a0 * acc[d4][rq * 4 + 1] + a1 * u.y) * inv;
        o.z = (a0 * acc[d4][rq * 4 + 2] + a1 * u.z) * inv;
        o.w = (a0 * acc[d4][rq * 4 + 3] + a1 * u.w) * inv;
        *(float4*)(orow + d) = o;
      }
    }
  }
  __syncthreads();

  if (kh == 1) {
#pragma unroll
    for (int d4 = 0; d4 < 4; ++d4) {
      float* dst = fb + ((wq * 4 + d4) * 64 + lane) * XS;
#pragma unroll
      for (int r4 = 0; r4 < 4; ++r4) {
        float4 v;
        v.x = acc[d4 + 4][r4 * 4 + 0]; v.y = acc[d4 + 4][r4 * 4 + 1];
        v.z = acc[d4 + 4][r4 * 4 + 2]; v.w = acc[d4 + 4][r4 * 4 + 3];
        *(float4*)(dst + r4 * 4) = v;
      }
    }
  }
  __syncthreads();

  if (kh == 0) {
#pragma unroll
    for (int d4 = 0; d4 < 4; ++d4) {
      const float* src = fb + ((wq * 4 + d4) * 64 + lane) * XS;
#pragma unroll
      for (int rq = 0; rq < 4; ++rq) {
        float4 u = *(const float4*)(src + rq * 4);
        int d = (d4 + 4) * 32 + rq * 8 + h * 4;
        float4 o;
        o.x = (a0 * acc[d4 + 4][rq * 4 + 0] + a1 * u.x) * inv;
        o.y = (a0 * acc[d4 + 4][rq * 4 + 1] + a1 * u.y) * inv;
        o.z = (a0 * acc[d4 + 4][rq * 4 + 2] + a1 * u.z) * inv;
        o.w = (a0 * acc[d4 + 4][rq * 4 + 3] + a1 * u.w) * inv;
        *(float4*)(orow + d) = o;
      }
    }
  }
}

// ---------------------------------------------------------------------------
extern "C" void kernel_launch(void* const* d_in, const int* in_sizes, int n_in,
                              void* d_out, int out_size, void* d_ws, size_t ws_size,
                              hipStream_t stream) {
  const float* enc = (const float*)d_in[0];
  const float* dec = (const float*)d_in[1];
  float* out = (float*)d_out;

  u16* ws_img = (u16*)d_ws;

  convert_enc<<<BN * (S / 64), 256, 0, stream>>>(enc, ws_img);
  attn_kernel<<<BN * (S / 128), 512, 0, stream>>>(ws_img, dec, out);
}